// Round 7
// baseline (172.549 us; speedup 1.0000x reference)
//
#include <hip/hip_runtime.h>

// LBP block — single fused kernel, 2 output rows per wave, NO DS ops in the
// channel loop's dependency chain (halo computed per-lane, not shuffled).
// block = 256 threads (4 waves) = (n, 8-row tile, group of 16 channels).
// Each lane holds 4 x-rows x 3 ch x (4 main cols as float4 + 2 halo scalars);
// the 16-channel loop is pure register VALU + 2 uniform ds_read_b128 (ews).
// y recompute across lanes/waves is bit-identical (same contract-off
// expression, same inputs). Stores are nontemporal (write-once stream).
//
// Numerics (do not change): y = (x0*cw0 + x1*cw1) + x2*cw2 sequentially with
// FMA contraction OFF to match the numpy reference; (c - s > 0) == (c > s)
// exactly for finite floats. Halo garbage (clamped loads at col 0 / col 255)
// feeds only border outputs, which are zeroed.

typedef float vfloat4 __attribute__((ext_vector_type(4)));  // nontemporal-ok

__global__ __launch_bounds__(256, 4) void lbp_all(
    const float* __restrict__ x,
    const float* __restrict__ conv_w,
    const float* __restrict__ w,
    float* __restrict__ out)
{
#pragma clang fp contract(off)
    const int n     = blockIdx.z;
    const int og    = blockIdx.y;            // channels og*16 .. og*16+15
    const int tid   = threadIdx.x;
    const int lane  = tid & 63;
    const int wv    = tid >> 6;              // wave 0..3
    const int col   = lane * 4;
    const int hrow0 = blockIdx.x * 8 + wv * 2;   // wave's first output row

    __shared__ float ews[128];               // exp(w) for this block's 16 ch
    if (tid < 128) ews[tid] = expf(w[og * 128 + tid]);

    const float* xn = x + (size_t)n * 3 * 65536;
    const int cl = (col == 0)   ? 0   : col - 1;   // halo col left (clamped)
    const int cr = (col == 252) ? 255 : col + 4;   // halo col right (clamped)

    // x rows hrow0-1 .. hrow0+2 (clamped), 3 input channels.
    vfloat4 xr[4][3];          // main 4 columns
    float   hl[4][3], hr[4][3];// halo columns col-1, col+4
    #pragma unroll
    for (int r = 0; r < 4; ++r) {
        int row = hrow0 - 1 + r;
        row = row < 0 ? 0 : (row > 255 ? 255 : row);
        #pragma unroll
        for (int ch = 0; ch < 3; ++ch) {
            const float* bp = xn + (ch * 256 + row) * 256;
            xr[r][ch] = *(const vfloat4*)(bp + col);
            hl[r][ch] = bp[cl];
            hr[r][ch] = bp[cr];
        }
    }

    if (og == 0) {  // copy channels 0..2; xr[1]=row hrow0, xr[2]=row hrow0+1
        #pragma unroll
        for (int ch = 0; ch < 3; ++ch) {
            float* cp = out + ((((size_t)n * 67 + ch) * 256 + hrow0) * 256 + col);
            __builtin_nontemporal_store(xr[1][ch], (vfloat4*)cp);
            __builtin_nontemporal_store(xr[2][ch], (vfloat4*)(cp + 256));
        }
    }

    __syncthreads();

    float* obase = out + ((((size_t)n * 67 + 3 + og * 16) * 256 + hrow0) * 256 + col);

    #pragma unroll 2
    for (int oi = 0; oi < 16; ++oi) {
        const int o = og * 16 + oi;
        const float cw0 = conv_w[o * 3 + 0];
        const float cw1 = conv_w[o * 3 + 1];
        const float cw2 = conv_w[o * 3 + 2];

        // Y[r][k] = y at row hrow0-1+r, col (col-1+k), k=0..5 — all per-lane.
        float Y[4][6];
        #pragma unroll
        for (int r = 0; r < 4; ++r) {
            Y[r][0] = hl[r][0]   * cw0 + hl[r][1]   * cw1 + hl[r][2]   * cw2;
            Y[r][1] = xr[r][0].x * cw0 + xr[r][1].x * cw1 + xr[r][2].x * cw2;
            Y[r][2] = xr[r][0].y * cw0 + xr[r][1].y * cw1 + xr[r][2].y * cw2;
            Y[r][3] = xr[r][0].z * cw0 + xr[r][1].z * cw1 + xr[r][2].z * cw2;
            Y[r][4] = xr[r][0].w * cw0 + xr[r][1].w * cw1 + xr[r][2].w * cw2;
            Y[r][5] = hr[r][0]   * cw0 + hr[r][1]   * cw1 + hr[r][2]   * cw2;
        }

        const vfloat4 ev0 = *(const vfloat4*)&ews[oi * 8];     // uniform addr
        const vfloat4 ev1 = *(const vfloat4*)&ews[oi * 8 + 4]; // -> 2x b128
        const float e0 = ev0.x, e1 = ev0.y, e2 = ev0.z, e3 = ev0.w;
        const float e4 = ev1.x, e5 = ev1.y, e6 = ev1.z, e7 = ev1.w;

        #pragma unroll
        for (int k = 0; k < 2; ++k) {        // the wave's two output rows
            const int hrow = hrow0 + k;
            float res[4];
            if (hrow == 0 || hrow == 255) {  // wave-uniform branch
                res[0] = res[1] = res[2] = res[3] = 0.f;
            } else {
                const float* up  = Y[k];
                const float* mid = Y[k + 1];
                const float* dn  = Y[k + 2];
                #pragma unroll
                for (int j = 0; j < 4; ++j) {
                    const float c = mid[j + 1];
                    float acc;
                    acc  = (c > up [j    ]) ? e0 : 0.f;   // (-1,-1)
                    acc += (c > up [j + 1]) ? e1 : 0.f;   // (-1, 0)
                    acc += (c > up [j + 2]) ? e2 : 0.f;   // (-1,+1)
                    acc += (c > mid[j    ]) ? e3 : 0.f;   // ( 0,-1)
                    acc += (c > dn [j    ]) ? e4 : 0.f;   // (+1,-1)
                    acc += (c > dn [j + 1]) ? e5 : 0.f;   // (+1, 0)
                    acc += (c > dn [j + 2]) ? e6 : 0.f;   // (+1,+1)
                    acc += (c > mid[j + 2]) ? e7 : 0.f;   // ( 0,+1)
                    res[j] = acc;
                }
                if (lane == 0)  res[0] = 0.f;   // col 0
                if (lane == 63) res[3] = 0.f;   // col 255
            }
            vfloat4 rv; rv.x = res[0]; rv.y = res[1]; rv.z = res[2]; rv.w = res[3];
            __builtin_nontemporal_store(
                rv, (vfloat4*)(obase + (size_t)oi * 65536 + (size_t)k * 256));
        }
    }
}

extern "C" void kernel_launch(void* const* d_in, const int* in_sizes, int n_in,
                              void* d_out, int out_size, void* d_ws, size_t ws_size,
                              hipStream_t stream) {
    const float* x      = (const float*)d_in[0];
    const float* conv_w = (const float*)d_in[1];
    const float* w      = (const float*)d_in[2];
    float* out          = (float*)d_out;

    dim3 grid(32, 4, 8);   // (8-row tiles, channel groups of 16, batch)
    dim3 block(256);
    hipLaunchKernelGGL(lbp_all, grid, block, 0, stream, x, conv_w, w, out);
}